// Round 2
// baseline (636.717 us; speedup 1.0000x reference)
//
#include <hip/hip_runtime.h>
#include <hip/hip_bf16.h>

using bf16 = __hip_bfloat16;
typedef __attribute__((ext_vector_type(8))) short bf16x8;   // 8 bf16 in 4 VGPRs
typedef __attribute__((ext_vector_type(4))) float f32x4;

#define DDIM 1024

__device__ __forceinline__ void gload16(const bf16* g, bf16* l) {
    __builtin_amdgcn_global_load_lds(
        (const __attribute__((address_space(1))) void*)g,
        (__attribute__((address_space(3))) void*)l, 16, 0, 0);
}

__device__ __forceinline__ short f2b(float f) {
    return (short)__bfloat16_as_ushort(__float2bfloat16(f));
}

// Per row o: dco[o] = rsqrt(sum_j (W[o,j]*w[j])^2 + 1e-8)
//            ad2[o] = noise_raw[o]*ns + b[o]
//            Wb[o,:] = bf16(W[o,:])
__global__ void prep_kernel(const float* __restrict__ W, const float* __restrict__ w,
                            const float* __restrict__ b, const float* __restrict__ nstr,
                            const float* __restrict__ nraw,
                            float* __restrict__ dco, float* __restrict__ ad2,
                            bf16* __restrict__ Wb) {
    int o = blockIdx.x;          // one wave per W row
    int lane = threadIdx.x;      // 64
    const float* Wrow = W + (size_t)o * DDIM;
    bf16* Wbrow = Wb + (size_t)o * DDIM;
    float s = 0.f;
    for (int j = lane; j < DDIM; j += 64) {
        float wv = Wrow[j];
        Wbrow[j] = __float2bfloat16(wv);
        float m = wv * w[j];
        s += m * m;
    }
#pragma unroll
    for (int off = 32; off; off >>= 1) s += __shfl_down(s, off);
    if (lane == 0) {
        dco[o] = rsqrtf(s + 1e-8f);
        ad2[o] = nraw[o] * nstr[0] + b[o];
    }
}

// C[n][o] = sum_j A[n][j] * W[o][j]
// PASS 1: A = x (fp32, reg-staged->bf16), C := (acc + b[col]) * w[col] -> t (bf16)
// PASS 2: A = t (bf16, gload_lds),        C := lrelu(acc*dco[col] + ad2[col]) -> out (fp32)
template<int PASS>
__global__ __launch_bounds__(256) void gemm_bt(
    const float* __restrict__ Af, const bf16* __restrict__ Ab,
    const bf16* __restrict__ B,
    const float* __restrict__ wst, const float* __restrict__ bias,
    const float* __restrict__ dco, const float* __restrict__ ad2,
    bf16* __restrict__ Cb, float* __restrict__ Cf)
{
    __shared__ bf16 lA[128 * 32];
    __shared__ bf16 lB[128 * 32];
    int tid  = threadIdx.x;
    int lane = tid & 63, wid = tid >> 6;
    int wr = wid >> 1, wc = wid & 1;          // 2x2 waves, each owns 64x64

    // bijective XCD swizzle: 4096 blocks % 8 == 0
    int bx  = blockIdx.x;
    int swz = (bx & 7) * 512 + (bx >> 3);
    int brow = swz >> 3;                      // 0..511
    int bcol = swz & 7;                       // 0..7

    const bf16* Bb = B + (size_t)bcol * 128 * DDIM;

    int srow = tid >> 2;                      // staging slice -> row s/4, col (s%4)*8
    int scol = (tid & 3) * 8;

    f32x4 acc[4][4];
#pragma unroll
    for (int m = 0; m < 4; ++m)
#pragma unroll
        for (int n = 0; n < 4; ++n) acc[m][n] = (f32x4){0.f, 0.f, 0.f, 0.f};

    int r16 = lane & 15, kh = lane >> 4;

    for (int k0 = 0; k0 < DDIM; k0 += 32) {
        if constexpr (PASS == 1) {
            const float* Abase = Af + (size_t)brow * 128 * DDIM + k0;
#pragma unroll
            for (int h = 0; h < 2; ++h) {
                int s = tid + h * 256;
                int row = s >> 2, kc = (s & 3) * 8;
                const float4* p = (const float4*)(Abase + (size_t)row * DDIM + kc);
                float4 v0 = p[0], v1 = p[1];
                bf16x8 pk;
                pk[0] = f2b(v0.x); pk[1] = f2b(v0.y); pk[2] = f2b(v0.z); pk[3] = f2b(v0.w);
                pk[4] = f2b(v1.x); pk[5] = f2b(v1.y); pk[6] = f2b(v1.z); pk[7] = f2b(v1.w);
                *(bf16x8*)(lA + s * 8) = pk;
            }
        } else {
            const bf16* Abase = Ab + (size_t)brow * 128 * DDIM + k0;
            gload16(Abase + (size_t)srow * DDIM + scol,        lA + tid * 8);
            gload16(Abase + (size_t)(srow + 64) * DDIM + scol, lA + (tid + 256) * 8);
        }
        gload16(Bb + (size_t)srow * DDIM + k0 + scol,        lB + tid * 8);
        gload16(Bb + (size_t)(srow + 64) * DDIM + k0 + scol, lB + (tid + 256) * 8);
        __syncthreads();

        bf16x8 aF[4], bF[4];
#pragma unroll
        for (int m = 0; m < 4; ++m) {
            aF[m] = *(const bf16x8*)(lA + ((wr * 64 + m * 16 + r16) * 32 + kh * 8));
            bF[m] = *(const bf16x8*)(lB + ((wc * 64 + m * 16 + r16) * 32 + kh * 8));
        }
#pragma unroll
        for (int m = 0; m < 4; ++m)
#pragma unroll
            for (int n = 0; n < 4; ++n)
                acc[m][n] = __builtin_amdgcn_mfma_f32_16x16x32_bf16(aF[m], bF[n], acc[m][n], 0, 0, 0);
        __syncthreads();
    }

    // C/D layout: col = lane&15, row = (lane>>4)*4 + j  [m89/m91 verified]
    int cb = lane & 15;
    int rb = (lane >> 4) * 4;
#pragma unroll
    for (int n = 0; n < 4; ++n) {
        int col = bcol * 128 + wc * 64 + n * 16 + cb;
        float colmul, coladd;
        if constexpr (PASS == 1) { colmul = wst[col]; coladd = bias[col]; }
        else                     { colmul = dco[col]; coladd = ad2[col]; }
#pragma unroll
        for (int m = 0; m < 4; ++m) {
#pragma unroll
            for (int j = 0; j < 4; ++j) {
                int row = wr * 64 + m * 16 + rb + j;
                size_t idx = ((size_t)brow * 128 + row) * DDIM + col;
                float v = acc[m][n][j];
                if constexpr (PASS == 1) {
                    v = (v + coladd) * colmul;
                    Cb[idx] = __float2bfloat16(v);
                } else {
                    v = v * colmul + coladd;
                    v = (v >= 0.f) ? v : 0.01f * v;
                    Cf[idx] = v;
                }
            }
        }
    }
}

extern "C" void kernel_launch(void* const* d_in, const int* in_sizes, int n_in,
                              void* d_out, int out_size, void* d_ws, size_t ws_size,
                              hipStream_t stream) {
    const float* x  = (const float*)d_in[0];   // [65536,1024] fp32
    const float* w  = (const float*)d_in[1];   // [1024]
    const float* W  = (const float*)d_in[2];   // [1024,1024]
    const float* b  = (const float*)d_in[3];   // [1024]
    const float* ns = (const float*)d_in[4];   // [1]
    const float* nr = (const float*)d_in[5];   // [1024]
    float* out = (float*)d_out;                // [65536,1024] fp32

    float* dco = (float*)d_ws;                        // 4 KB
    float* ad2 = dco + DDIM;                          // 4 KB
    bf16*  Wb  = (bf16*)((char*)d_ws + 8192);         // 2 MB
    bf16*  t   = (bf16*)((char*)d_ws + 8192 + 2097152); // 128 MB

    int M = in_sizes[0] / DDIM;               // 65536
    int grid = (M / 128) * (DDIM / 128);      // 4096

    prep_kernel<<<DDIM, 64, 0, stream>>>(W, w, b, ns, nr, dco, ad2, Wb);
    gemm_bt<1><<<grid, 256, 0, stream>>>(x, nullptr, Wb, w, b, dco, ad2, t, nullptr);
    gemm_bt<2><<<grid, 256, 0, stream>>>(nullptr, t, Wb, w, b, dco, ad2, nullptr, out);
}

// Round 3
// 507.234 us; speedup vs baseline: 1.2553x; 1.2553x over previous
//
#include <hip/hip_runtime.h>
#include <hip/hip_bf16.h>

using bf16 = __hip_bfloat16;
typedef __attribute__((ext_vector_type(8))) short bf16x8;   // 8 bf16 in 4 VGPRs
typedef __attribute__((ext_vector_type(4))) float f32x4;

#define DDIM 1024

__device__ __forceinline__ void gload16(const bf16* g, bf16* l) {
    __builtin_amdgcn_global_load_lds(
        (const __attribute__((address_space(1))) void*)g,
        (__attribute__((address_space(3))) void*)l, 16, 0, 0);
}

__device__ __forceinline__ short f2b(float f) {
    return (short)__bfloat16_as_ushort(__float2bfloat16(f));
}

// Per row o: dco[o] = rsqrt(sum_j (W[o,j]*w[j])^2 + 1e-8)
//            ad2[o] = noise_raw[o]*ns + b[o];  Wb[o,:] = bf16(W[o,:])
__global__ void prep_kernel(const float* __restrict__ W, const float* __restrict__ w,
                            const float* __restrict__ b, const float* __restrict__ nstr,
                            const float* __restrict__ nraw,
                            float* __restrict__ dco, float* __restrict__ ad2,
                            bf16* __restrict__ Wb) {
    int o = blockIdx.x;
    int lane = threadIdx.x;
    const float* Wrow = W + (size_t)o * DDIM;
    bf16* Wbrow = Wb + (size_t)o * DDIM;
    float s = 0.f;
    for (int j = lane; j < DDIM; j += 64) {
        float wv = Wrow[j];
        Wbrow[j] = __float2bfloat16(wv);
        float m = wv * w[j];
        s += m * m;
    }
#pragma unroll
    for (int off = 32; off; off >>= 1) s += __shfl_down(s, off);
    if (lane == 0) {
        dco[o] = rsqrtf(s + 1e-8f);
        ad2[o] = nraw[o] * nstr[0] + b[o];
    }
}

// C[n][o] = sum_j A[n][j] * W[o][j], 128x128 tile, BK=32, double-buffered LDS,
// one barrier per K-iter, next-tile stage issued before current-tile compute.
// PASS 1: A = x (fp32, reg-staged: load-early/write-late), C := (acc+b[col])*w[col] -> t (bf16)
// PASS 2: A = t (bf16, gload_lds),                          C := lrelu(acc*dco+ad2) -> out (fp32)
template<int PASS>
__global__ __launch_bounds__(256, 4) void gemm_bt(
    const float* __restrict__ Af, const bf16* __restrict__ Ab,
    const bf16* __restrict__ B,
    const float* __restrict__ wst, const float* __restrict__ bias,
    const float* __restrict__ dco, const float* __restrict__ ad2,
    bf16* __restrict__ Cb, float* __restrict__ Cf)
{
    __shared__ bf16 lA[2][128 * 32];
    __shared__ bf16 lB[2][128 * 32];
    int tid  = threadIdx.x;
    int lane = tid & 63, wid = tid >> 6;
    int wr = wid >> 1, wc = wid & 1;          // 2x2 waves, each owns 64x64

    // bijective XCD swizzle: 4096 blocks % 8 == 0
    int bx  = blockIdx.x;
    int swz = (bx & 7) * 512 + (bx >> 3);
    int brow = swz >> 3;                      // 0..511
    int bcol = swz & 7;                       // 0..7

    const bf16* Bb = B + (size_t)bcol * 128 * DDIM;
    const float* Afb = Af + (size_t)brow * 128 * DDIM;
    const bf16*  Abb = Ab + (size_t)brow * 128 * DDIM;

    int srow = tid >> 2;                      // staging slice -> row s/4, col (s%4)*8
    int scol = (tid & 3) * 8;

    f32x4 acc[4][4];
#pragma unroll
    for (int m = 0; m < 4; ++m)
#pragma unroll
        for (int n = 0; n < 4; ++n) acc[m][n] = (f32x4){0.f, 0.f, 0.f, 0.f};

    int r16 = lane & 15, kh = lane >> 4;

    // PASS1 A-register staging (named, no runtime-indexed arrays)
    float4 rA0a, rA0b, rA1a, rA1b;

    // ---- prologue: stage tile 0 into buf 0 ----
    if constexpr (PASS == 1) {
        const float* p0 = Afb + (size_t)srow * DDIM + scol;
        const float* p1 = Afb + (size_t)(srow + 64) * DDIM + scol;
        rA0a = ((const float4*)p0)[0]; rA0b = ((const float4*)p0)[1];
        rA1a = ((const float4*)p1)[0]; rA1b = ((const float4*)p1)[1];
        gload16(Bb + (size_t)srow * DDIM + scol,        lB[0] + tid * 8);
        gload16(Bb + (size_t)(srow + 64) * DDIM + scol, lB[0] + (tid + 256) * 8);
        bf16x8 pk;
        pk[0]=f2b(rA0a.x); pk[1]=f2b(rA0a.y); pk[2]=f2b(rA0a.z); pk[3]=f2b(rA0a.w);
        pk[4]=f2b(rA0b.x); pk[5]=f2b(rA0b.y); pk[6]=f2b(rA0b.z); pk[7]=f2b(rA0b.w);
        *(bf16x8*)(lA[0] + tid * 8) = pk;
        pk[0]=f2b(rA1a.x); pk[1]=f2b(rA1a.y); pk[2]=f2b(rA1a.z); pk[3]=f2b(rA1a.w);
        pk[4]=f2b(rA1b.x); pk[5]=f2b(rA1b.y); pk[6]=f2b(rA1b.z); pk[7]=f2b(rA1b.w);
        *(bf16x8*)(lA[0] + (tid + 256) * 8) = pk;
    } else {
        gload16(Abb + (size_t)srow * DDIM + scol,        lA[0] + tid * 8);
        gload16(Abb + (size_t)(srow + 64) * DDIM + scol, lA[0] + (tid + 256) * 8);
        gload16(Bb  + (size_t)srow * DDIM + scol,        lB[0] + tid * 8);
        gload16(Bb  + (size_t)(srow + 64) * DDIM + scol, lB[0] + (tid + 256) * 8);
    }
    __syncthreads();

    int cur = 0;
    for (int t = 0; t < DDIM / 32; ++t) {
        int k0n = (t + 1) * 32;
        bool pf = (t < DDIM / 32 - 1);        // wave-uniform
        int nxt = cur ^ 1;

        // ---- issue next-tile staging BEFORE compute ----
        if (pf) {
            gload16(Bb + (size_t)srow * DDIM + k0n + scol,        lB[nxt] + tid * 8);
            gload16(Bb + (size_t)(srow + 64) * DDIM + k0n + scol, lB[nxt] + (tid + 256) * 8);
            if constexpr (PASS == 1) {
                const float* p0 = Afb + (size_t)srow * DDIM + k0n + scol;
                const float* p1 = Afb + (size_t)(srow + 64) * DDIM + k0n + scol;
                rA0a = ((const float4*)p0)[0]; rA0b = ((const float4*)p0)[1];
                rA1a = ((const float4*)p1)[0]; rA1b = ((const float4*)p1)[1];
            } else {
                gload16(Abb + (size_t)srow * DDIM + k0n + scol,        lA[nxt] + tid * 8);
                gload16(Abb + (size_t)(srow + 64) * DDIM + k0n + scol, lA[nxt] + (tid + 256) * 8);
            }
        }

        // ---- compute current tile ----
        {
            const bf16* la = lA[cur];
            const bf16* lb = lB[cur];
            bf16x8 aF[4], bF[4];
#pragma unroll
            for (int m = 0; m < 4; ++m) {
                aF[m] = *(const bf16x8*)(la + ((wr * 64 + m * 16 + r16) * 32 + kh * 8));
                bF[m] = *(const bf16x8*)(lb + ((wc * 64 + m * 16 + r16) * 32 + kh * 8));
            }
#pragma unroll
            for (int m = 0; m < 4; ++m)
#pragma unroll
                for (int n = 0; n < 4; ++n)
                    acc[m][n] = __builtin_amdgcn_mfma_f32_16x16x32_bf16(aF[m], bF[n], acc[m][n], 0, 0, 0);
        }

        // ---- PASS1: convert + LDS-write the prefetched A regs (loads had MFMA phase to land) ----
        if (pf) {
            if constexpr (PASS == 1) {
                bf16x8 pk;
                pk[0]=f2b(rA0a.x); pk[1]=f2b(rA0a.y); pk[2]=f2b(rA0a.z); pk[3]=f2b(rA0a.w);
                pk[4]=f2b(rA0b.x); pk[5]=f2b(rA0b.y); pk[6]=f2b(rA0b.z); pk[7]=f2b(rA0b.w);
                *(bf16x8*)(lA[nxt] + tid * 8) = pk;
                pk[0]=f2b(rA1a.x); pk[1]=f2b(rA1a.y); pk[2]=f2b(rA1a.z); pk[3]=f2b(rA1a.w);
                pk[4]=f2b(rA1b.x); pk[5]=f2b(rA1b.y); pk[6]=f2b(rA1b.z); pk[7]=f2b(rA1b.w);
                *(bf16x8*)(lA[nxt] + (tid + 256) * 8) = pk;
            }
        }
        __syncthreads();
        cur ^= 1;
    }

    // epilogue: C/D layout col = lane&15, row = (lane>>4)*4 + j  [m89/m91 verified]
    int cb = lane & 15;
    int rb = (lane >> 4) * 4;
#pragma unroll
    for (int n = 0; n < 4; ++n) {
        int col = bcol * 128 + wc * 64 + n * 16 + cb;
        float colmul, coladd;
        if constexpr (PASS == 1) { colmul = wst[col]; coladd = bias[col]; }
        else                     { colmul = dco[col]; coladd = ad2[col]; }
#pragma unroll
        for (int m = 0; m < 4; ++m) {
#pragma unroll
            for (int j = 0; j < 4; ++j) {
                int row = wr * 64 + m * 16 + rb + j;
                size_t idx = ((size_t)brow * 128 + row) * DDIM + col;
                float v = acc[m][n][j];
                if constexpr (PASS == 1) {
                    v = (v + coladd) * colmul;
                    Cb[idx] = __float2bfloat16(v);
                } else {
                    v = v * colmul + coladd;
                    v = (v >= 0.f) ? v : 0.01f * v;
                    Cf[idx] = v;
                }
            }
        }
    }
}

extern "C" void kernel_launch(void* const* d_in, const int* in_sizes, int n_in,
                              void* d_out, int out_size, void* d_ws, size_t ws_size,
                              hipStream_t stream) {
    const float* x  = (const float*)d_in[0];   // [65536,1024] fp32
    const float* w  = (const float*)d_in[1];   // [1024]
    const float* W  = (const float*)d_in[2];   // [1024,1024]
    const float* b  = (const float*)d_in[3];   // [1024]
    const float* ns = (const float*)d_in[4];   // [1]
    const float* nr = (const float*)d_in[5];   // [1024]
    float* out = (float*)d_out;                // [65536,1024] fp32

    float* dco = (float*)d_ws;                          // 4 KB
    float* ad2 = dco + DDIM;                            // 4 KB
    bf16*  Wb  = (bf16*)((char*)d_ws + 8192);           // 2 MB
    bf16*  t   = (bf16*)((char*)d_ws + 8192 + 2097152); // 128 MB

    int M = in_sizes[0] / DDIM;               // 65536
    int grid = (M / 128) * (DDIM / 128);      // 4096

    prep_kernel<<<DDIM, 64, 0, stream>>>(W, w, b, ns, nr, dco, ad2, Wb);
    gemm_bt<1><<<grid, 256, 0, stream>>>(x, nullptr, Wb, w, b, dco, ad2, t, nullptr);
    gemm_bt<2><<<grid, 256, 0, stream>>>(nullptr, t, Wb, w, b, dco, ad2, nullptr, out);
}

// Round 4
// 455.424 us; speedup vs baseline: 1.3981x; 1.1138x over previous
//
#include <hip/hip_runtime.h>
#include <hip/hip_bf16.h>

using bf16 = __hip_bfloat16;
typedef __attribute__((ext_vector_type(8))) short bf16x8;
typedef __attribute__((ext_vector_type(4))) float f32x4;

#define DDIM 1024

__device__ __forceinline__ void gload16(const bf16* g, bf16* l) {
    __builtin_amdgcn_global_load_lds(
        (const __attribute__((address_space(1))) void*)g,
        (__attribute__((address_space(3))) void*)l, 16, 0, 0);
}
__device__ __forceinline__ short f2b(float f) {
    return (short)__bfloat16_as_ushort(__float2bfloat16(f));
}

__global__ void prep_kernel(const float* __restrict__ W, const float* __restrict__ w,
                            const float* __restrict__ b, const float* __restrict__ nstr,
                            const float* __restrict__ nraw,
                            float* __restrict__ dco, float* __restrict__ ad2,
                            bf16* __restrict__ Wb) {
    int o = blockIdx.x;
    int lane = threadIdx.x;
    const float* Wrow = W + (size_t)o * DDIM;
    bf16* Wbrow = Wb + (size_t)o * DDIM;
    float s = 0.f;
    for (int j = lane; j < DDIM; j += 64) {
        float wv = Wrow[j];
        Wbrow[j] = __float2bfloat16(wv);
        float m = wv * w[j];
        s += m * m;
    }
#pragma unroll
    for (int off = 32; off; off >>= 1) s += __shfl_down(s, off);
    if (lane == 0) {
        dco[o] = rsqrtf(s + 1e-8f);
        ad2[o] = nraw[o] * nstr[0] + b[o];
    }
}

// ---- 256x256x(BK=64) 8-phase GEMM, C[n][o] = sum_j A[n][j]*W[o][j] ----
// 8 waves (2M x 4N), per-wave C = 128x64. LDS [buf][ks][256][32] bf16, XOR slot^=(row&3).
#define BAR()  do { asm volatile("" ::: "memory"); __builtin_amdgcn_s_barrier(); asm volatile("" ::: "memory"); } while (0)
#define VMW(n) asm volatile("s_waitcnt vmcnt(" #n ")" ::: "memory")
#define LGW()  asm volatile("s_waitcnt lgkmcnt(0)" ::: "memory")

template<int PASS>
__global__ __launch_bounds__(512, 2) void gemm8p(
    const float* __restrict__ Af, const bf16* __restrict__ Ab,
    const bf16* __restrict__ Bw,
    const float* __restrict__ wst, const float* __restrict__ bias,
    const float* __restrict__ dco, const float* __restrict__ ad2,
    bf16* __restrict__ Cb, float* __restrict__ Cf)
{
    __shared__ bf16 sA[2][2][256 * 32];   // 64 KiB
    __shared__ bf16 sB[2][2][256 * 32];   // 64 KiB

    const int tid  = threadIdx.x;
    const int lane = tid & 63;
    const int wid  = tid >> 6;
    const int wr   = wid >> 2, wc = wid & 3;      // 2 x 4 waves
    const int r16  = lane & 15, kh = lane >> 4;
    const int fso  = (kh ^ (r16 & 3)) * 8;        // swizzled frag slot offset (elems)

    int bx  = blockIdx.x;                          // 1024 blocks
    int swz = (bx & 7) * 128 + (bx >> 3);          // bijective XCD swizzle (1024%8==0)
    int brow = swz >> 2, bcol = swz & 3;           // 256 x 4

    const float* Asrc_f = Af + (size_t)(brow * 256) * DDIM;
    const bf16*  Asrc_b = Ab + (size_t)(brow * 256) * DDIM;
    const bf16*  Bsrc   = Bw + (size_t)(bcol * 256) * DDIM;

    const int sr  = tid >> 2;                      // staging row 0..127 (and +128)
    const int ssl = (tid & 3) ^ (sr & 3);          // swizzled 16B slot (same for sr+128)

    f32x4 acc[8][4];
#pragma unroll
    for (int m = 0; m < 8; ++m)
#pragma unroll
        for (int n = 0; n < 4; ++n) acc[m][n] = (f32x4){0.f, 0.f, 0.f, 0.f};

    bf16x8 aF[4], bF[4];
    float4 gA0, gA1, gA2, gA3;   // reg group A (PASS1)
    float4 gB0, gB1, gB2, gB3;   // reg group B (PASS1)

#define STAGE_B(buf, kt, ks) do { \
    const bf16* _s = Bsrc + (size_t)sr * DDIM + ((kt) * 64 + (ks) * 32 + ssl * 8); \
    gload16(_s,               &sB[buf][ks][tid * 8]); \
    gload16(_s + 128 * DDIM,  &sB[buf][ks][(tid + 512) * 8]); \
} while (0)

#define STAGE_A_G(buf, kt, ks) do { \
    const bf16* _s = Asrc_b + (size_t)sr * DDIM + ((kt) * 64 + (ks) * 32 + ssl * 8); \
    gload16(_s,               &sA[buf][ks][tid * 8]); \
    gload16(_s + 128 * DDIM,  &sA[buf][ks][(tid + 512) * 8]); \
} while (0)

#define LOAD_A_F(g0, g1, g2, g3, kt, ks) do { \
    const float* _p = Asrc_f + (size_t)sr * DDIM + ((kt) * 64 + (ks) * 32 + (tid & 3) * 8); \
    g0 = ((const float4*)_p)[0]; g1 = ((const float4*)_p)[1]; \
    const float* _q = _p + 128 * DDIM; \
    g2 = ((const float4*)_q)[0]; g3 = ((const float4*)_q)[1]; \
} while (0)

#define WRITE_A(buf, ks, g0, g1, g2, g3) do { \
    bf16x8 _pk; \
    _pk[0]=f2b(g0.x); _pk[1]=f2b(g0.y); _pk[2]=f2b(g0.z); _pk[3]=f2b(g0.w); \
    _pk[4]=f2b(g1.x); _pk[5]=f2b(g1.y); _pk[6]=f2b(g1.z); _pk[7]=f2b(g1.w); \
    *(bf16x8*)&sA[buf][ks][sr * 32 + ssl * 8] = _pk; \
    _pk[0]=f2b(g2.x); _pk[1]=f2b(g2.y); _pk[2]=f2b(g2.z); _pk[3]=f2b(g2.w); \
    _pk[4]=f2b(g3.x); _pk[5]=f2b(g3.y); _pk[6]=f2b(g3.z); _pk[7]=f2b(g3.w); \
    *(bf16x8*)&sA[buf][ks][(sr + 128) * 32 + ssl * 8] = _pk; \
} while (0)

#define RD_A(buf, ks, mh) do { \
    _Pragma("unroll") for (int _m = 0; _m < 4; ++_m) \
        aF[_m] = *(const bf16x8*)&sA[buf][ks][(wr * 128 + (mh) * 64 + _m * 16 + r16) * 32 + fso]; \
} while (0)

#define RD_B(buf, ks) do { \
    _Pragma("unroll") for (int _n = 0; _n < 4; ++_n) \
        bF[_n] = *(const bf16x8*)&sB[buf][ks][(wc * 64 + _n * 16 + r16) * 32 + fso]; \
} while (0)

#define MFMA16(mh) do { \
    __builtin_amdgcn_s_setprio(1); \
    _Pragma("unroll") for (int _m = 0; _m < 4; ++_m) \
    _Pragma("unroll") for (int _n = 0; _n < 4; ++_n) \
        acc[(mh) * 4 + _m][_n] = __builtin_amdgcn_mfma_f32_16x16x32_bf16(aF[_m], bF[_n], acc[(mh)*4+_m][_n], 0, 0, 0); \
    __builtin_amdgcn_s_setprio(0); \
} while (0)

    // ---------------- prologue ----------------
    if constexpr (PASS == 1) {
        LOAD_A_F(gA0, gA1, gA2, gA3, 0, 0);
        LOAD_A_F(gB0, gB1, gB2, gB3, 0, 1);
        STAGE_B(0, 0, 0); STAGE_B(0, 0, 1);
        WRITE_A(0, 0, gA0, gA1, gA2, gA3);
        WRITE_A(0, 1, gB0, gB1, gB2, gB3);
        LOAD_A_F(gA0, gA1, gA2, gA3, 1, 0);    // consumed at ph0 (t1.AK0)
        LOAD_A_F(gB0, gB1, gB2, gB3, 1, 1);    // consumed at ph2 (t1.AK1)
        LGW();
        VMW(8);                                 // retire t0.B halves; keep LA groups in flight
        BAR();
    } else {
        STAGE_A_G(0, 0, 0); STAGE_B(0, 0, 0);
        STAGE_A_G(0, 0, 1); STAGE_B(0, 0, 1);
        VMW(4);                                 // t0.K0 landed; t0.K1 in flight
        BAR();
    }

    // ---------------- main loop: 8 iters x 2 K-tiles ----------------
    for (int i = 0; i < 8; ++i) {
        int t1 = 2 * i + 1;
        int t2 = 2 * i + 2; if (t2 > 15) t2 = 15;   // tail clamp (stages never read)
        int t3 = 2 * i + 3; if (t3 > 15) t3 = 15;

        // ph0: compute (t0 buf0, ks0, mh0); stage t1.AK0 -> buf1
        RD_A(0, 0, 0); RD_B(0, 0);
        if constexpr (PASS == 1) {
            WRITE_A(1, 0, gA0, gA1, gA2, gA3);
            LOAD_A_F(gA0, gA1, gA2, gA3, t2, 0);
            LGW();
        } else {
            STAGE_A_G(1, t1, 0);
        }
        BAR(); MFMA16(0); BAR();

        // ph1: (ks0, mh1); stage t1.BK0 -> buf1
        RD_A(0, 0, 1);
        STAGE_B(1, t1, 0);
        BAR(); MFMA16(1);
        if constexpr (PASS == 1) { VMW(6); } else { VMW(4); }
        BAR();

        // ph2: (ks1, mh0); stage t1.AK1 -> buf1
        RD_A(0, 1, 0); RD_B(0, 1);
        if constexpr (PASS == 1) {
            WRITE_A(1, 1, gB0, gB1, gB2, gB3);
            LOAD_A_F(gB0, gB1, gB2, gB3, t2, 1);
            LGW();
        } else {
            STAGE_A_G(1, t1, 1);
        }
        BAR(); MFMA16(0); BAR();

        // ph3: (ks1, mh1); stage t1.BK1 -> buf1
        RD_A(0, 1, 1);
        STAGE_B(1, t1, 1);
        BAR(); MFMA16(1);
        if constexpr (PASS == 1) { VMW(6); } else { VMW(4); }
        BAR();

        // ph4: compute (t1 buf1, ks0, mh0); stage t2.AK0 -> buf0
        RD_A(1, 0, 0); RD_B(1, 0);
        if constexpr (PASS == 1) {
            WRITE_A(0, 0, gA0, gA1, gA2, gA3);
            LOAD_A_F(gA0, gA1, gA2, gA3, t3, 0);
            LGW();
        } else {
            STAGE_A_G(0, t2, 0);
        }
        BAR(); MFMA16(0); BAR();

        // ph5: (ks0, mh1); stage t2.BK0 -> buf0
        RD_A(1, 0, 1);
        STAGE_B(0, t2, 0);
        BAR(); MFMA16(1);
        if constexpr (PASS == 1) { VMW(6); } else { VMW(4); }
        BAR();

        // ph6: (ks1, mh0); stage t2.AK1 -> buf0
        RD_A(1, 1, 0); RD_B(1, 1);
        if constexpr (PASS == 1) {
            WRITE_A(0, 1, gB0, gB1, gB2, gB3);
            LOAD_A_F(gB0, gB1, gB2, gB3, t3, 1);
            LGW();
        } else {
            STAGE_A_G(0, t2, 1);
        }
        BAR(); MFMA16(0); BAR();

        // ph7: (ks1, mh1); stage t2.BK1 -> buf0
        RD_A(1, 1, 1);
        STAGE_B(0, t2, 1);
        BAR(); MFMA16(1);
        if constexpr (PASS == 1) { VMW(6); } else { VMW(4); }
        BAR();
    }

    // ---------------- epilogue ----------------
    int crb = brow * 256 + wr * 128 + kh * 4;
    int ccb = bcol * 256 + wc * 64 + r16;
#pragma unroll
    for (int n = 0; n < 4; ++n) {
        int col = ccb + n * 16;
        float cm, ca;
        if constexpr (PASS == 1) { cm = wst[col]; ca = bias[col]; }
        else                     { cm = dco[col]; ca = ad2[col]; }
#pragma unroll
        for (int m = 0; m < 8; ++m) {
#pragma unroll
            for (int j = 0; j < 4; ++j) {
                size_t idx = (size_t)(crb + m * 16 + j) * DDIM + col;
                float v = acc[m][n][j];
                if constexpr (PASS == 1) {
                    v = (v + ca) * cm;
                    Cb[idx] = __float2bfloat16(v);
                } else {
                    v = v * cm + ca;
                    v = (v >= 0.f) ? v : 0.01f * v;
                    Cf[idx] = v;
                }
            }
        }
    }
#undef STAGE_B
#undef STAGE_A_G
#undef LOAD_A_F
#undef WRITE_A
#undef RD_A
#undef RD_B
#undef MFMA16
}

extern "C" void kernel_launch(void* const* d_in, const int* in_sizes, int n_in,
                              void* d_out, int out_size, void* d_ws, size_t ws_size,
                              hipStream_t stream) {
    const float* x  = (const float*)d_in[0];
    const float* w  = (const float*)d_in[1];
    const float* W  = (const float*)d_in[2];
    const float* b  = (const float*)d_in[3];
    const float* ns = (const float*)d_in[4];
    const float* nr = (const float*)d_in[5];
    float* out = (float*)d_out;

    float* dco = (float*)d_ws;
    float* ad2 = dco + DDIM;
    bf16*  Wb  = (bf16*)((char*)d_ws + 8192);
    bf16*  t   = (bf16*)((char*)d_ws + 8192 + 2097152);

    int M = in_sizes[0] / DDIM;                     // 65536
    int grid = (M / 256) * (DDIM / 256);            // 1024

    prep_kernel<<<DDIM, 64, 0, stream>>>(W, w, b, ns, nr, dco, ad2, Wb);
    gemm8p<1><<<grid, 512, 0, stream>>>(x, nullptr, Wb, w, b, dco, ad2, t, nullptr);
    gemm8p<2><<<grid, 512, 0, stream>>>(nullptr, t, Wb, w, b, dco, ad2, nullptr, out);
}

// Round 5
// 445.780 us; speedup vs baseline: 1.4283x; 1.0216x over previous
//
#include <hip/hip_runtime.h>
#include <hip/hip_bf16.h>

using bf16 = __hip_bfloat16;
typedef __attribute__((ext_vector_type(8))) short bf16x8;
typedef __attribute__((ext_vector_type(4))) float f32x4;

#define DDIM 1024

__device__ __forceinline__ void gload16(const bf16* g, bf16* l) {
    __builtin_amdgcn_global_load_lds(
        (const __attribute__((address_space(1))) void*)g,
        (__attribute__((address_space(3))) void*)l, 16, 0, 0);
}
__device__ __forceinline__ short f2b(float f) {
    return (short)__bfloat16_as_ushort(__float2bfloat16(f));
}

__global__ void prep_kernel(const float* __restrict__ W, const float* __restrict__ w,
                            const float* __restrict__ b, const float* __restrict__ nstr,
                            const float* __restrict__ nraw,
                            float* __restrict__ dco, float* __restrict__ ad2,
                            bf16* __restrict__ Wb) {
    int o = blockIdx.x;
    int lane = threadIdx.x;
    const float* Wrow = W + (size_t)o * DDIM;
    bf16* Wbrow = Wb + (size_t)o * DDIM;
    float s = 0.f;
    for (int j = lane; j < DDIM; j += 64) {
        float wv = Wrow[j];
        Wbrow[j] = __float2bfloat16(wv);
        float m = wv * w[j];
        s += m * m;
    }
#pragma unroll
    for (int off = 32; off; off >>= 1) s += __shfl_down(s, off);
    if (lane == 0) {
        dco[o] = rsqrtf(s + 1e-8f);
        ad2[o] = nraw[o] * nstr[0] + b[o];
    }
}

// ---- 256x256x(BK=64) 8-phase GEMM, C[n][o] = sum_j A[n][j]*W[o][j] ----
// 8 waves (2M x 4N), per-wave C = 128x64. LDS [buf][ks][256][32] bf16.
// Swizzle: 16B slot s at row r stored at s ^ ((r>>1)&3)  [bank-quad q = 4(r&1) + s^key
// hits all 8 quads over 8 consecutive rows -> 2-way = free; (r&3) key was 4-way-conflicted]
#define BAR()  do { asm volatile("" ::: "memory"); __builtin_amdgcn_s_barrier(); asm volatile("" ::: "memory"); } while (0)
#define VMW(n) asm volatile("s_waitcnt vmcnt(" #n ")" ::: "memory")
#define LGW()  asm volatile("s_waitcnt lgkmcnt(0)" ::: "memory")

template<int PASS>
__global__ __launch_bounds__(512, 2) void gemm8p(
    const float* __restrict__ Af, const bf16* __restrict__ Ab,
    const bf16* __restrict__ Bw,
    const float* __restrict__ wst, const float* __restrict__ bias,
    const float* __restrict__ dco, const float* __restrict__ ad2,
    bf16* __restrict__ Cb, float* __restrict__ Cf)
{
    __shared__ bf16 sA[2][2][256 * 32];   // 64 KiB
    __shared__ bf16 sB[2][2][256 * 32];   // 64 KiB

    const int tid  = threadIdx.x;
    const int lane = tid & 63;
    const int wid  = tid >> 6;
    const int wr   = wid >> 2, wc = wid & 3;      // 2 x 4 waves
    const int r16  = lane & 15, kh = lane >> 4;
    const int fso  = (kh ^ ((r16 >> 1) & 3)) * 8; // swizzled frag slot offset (elems)

    int bx  = blockIdx.x;                          // 1024 blocks
    int swz = (bx & 7) * 128 + (bx >> 3);          // bijective XCD swizzle (1024%8==0)
    int brow = swz >> 2, bcol = swz & 3;           // 256 x 4

    const float* Asrc_f = Af + (size_t)(brow * 256) * DDIM;
    const bf16*  Asrc_b = Ab + (size_t)(brow * 256) * DDIM;
    const bf16*  Bsrc   = Bw + (size_t)(bcol * 256) * DDIM;

    const int sr  = tid >> 2;                      // staging row 0..127 (and +128)
    const int ssl = (tid & 3) ^ ((sr >> 1) & 3);   // swizzled 16B source slot (key same for sr+128)

    f32x4 acc[8][4];
#pragma unroll
    for (int m = 0; m < 8; ++m)
#pragma unroll
        for (int n = 0; n < 4; ++n) acc[m][n] = (f32x4){0.f, 0.f, 0.f, 0.f};

    bf16x8 aF[4], bF[4];
    float4 gA0, gA1, gA2, gA3;   // reg group A (PASS1)
    float4 gB0, gB1, gB2, gB3;   // reg group B (PASS1)

#define STAGE_B(buf, kt, ks) do { \
    const bf16* _s = Bsrc + (size_t)sr * DDIM + ((kt) * 64 + (ks) * 32 + ssl * 8); \
    gload16(_s,               &sB[buf][ks][tid * 8]); \
    gload16(_s + 128 * DDIM,  &sB[buf][ks][(tid + 512) * 8]); \
} while (0)

#define STAGE_A_G(buf, kt, ks) do { \
    const bf16* _s = Asrc_b + (size_t)sr * DDIM + ((kt) * 64 + (ks) * 32 + ssl * 8); \
    gload16(_s,               &sA[buf][ks][tid * 8]); \
    gload16(_s + 128 * DDIM,  &sA[buf][ks][(tid + 512) * 8]); \
} while (0)

#define LOAD_A_F(g0, g1, g2, g3, kt, ks) do { \
    const float* _p = Asrc_f + (size_t)sr * DDIM + ((kt) * 64 + (ks) * 32 + (tid & 3) * 8); \
    g0 = ((const float4*)_p)[0]; g1 = ((const float4*)_p)[1]; \
    const float* _q = _p + 128 * DDIM; \
    g2 = ((const float4*)_q)[0]; g3 = ((const float4*)_q)[1]; \
} while (0)

#define WRITE_A(buf, ks, g0, g1, g2, g3) do { \
    bf16x8 _pk; \
    _pk[0]=f2b(g0.x); _pk[1]=f2b(g0.y); _pk[2]=f2b(g0.z); _pk[3]=f2b(g0.w); \
    _pk[4]=f2b(g1.x); _pk[5]=f2b(g1.y); _pk[6]=f2b(g1.z); _pk[7]=f2b(g1.w); \
    *(bf16x8*)&sA[buf][ks][sr * 32 + ssl * 8] = _pk; \
    _pk[0]=f2b(g2.x); _pk[1]=f2b(g2.y); _pk[2]=f2b(g2.z); _pk[3]=f2b(g2.w); \
    _pk[4]=f2b(g3.x); _pk[5]=f2b(g3.y); _pk[6]=f2b(g3.z); _pk[7]=f2b(g3.w); \
    *(bf16x8*)&sA[buf][ks][(sr + 128) * 32 + ssl * 8] = _pk; \
} while (0)

#define RD_A(buf, ks, mh) do { \
    _Pragma("unroll") for (int _m = 0; _m < 4; ++_m) \
        aF[_m] = *(const bf16x8*)&sA[buf][ks][(wr * 128 + (mh) * 64 + _m * 16 + r16) * 32 + fso]; \
} while (0)

#define RD_B(buf, ks) do { \
    _Pragma("unroll") for (int _n = 0; _n < 4; ++_n) \
        bF[_n] = *(const bf16x8*)&sB[buf][ks][(wc * 64 + _n * 16 + r16) * 32 + fso]; \
} while (0)

#define MFMA16(mh) do { \
    __builtin_amdgcn_s_setprio(1); \
    _Pragma("unroll") for (int _m = 0; _m < 4; ++_m) \
    _Pragma("unroll") for (int _n = 0; _n < 4; ++_n) \
        acc[(mh) * 4 + _m][_n] = __builtin_amdgcn_mfma_f32_16x16x32_bf16(aF[_m], bF[_n], acc[(mh)*4+_m][_n], 0, 0, 0); \
    __builtin_amdgcn_s_setprio(0); \
} while (0)

    // ---------------- prologue ----------------
    if constexpr (PASS == 1) {
        LOAD_A_F(gA0, gA1, gA2, gA3, 0, 0);
        LOAD_A_F(gB0, gB1, gB2, gB3, 0, 1);
        STAGE_B(0, 0, 0); STAGE_B(0, 0, 1);
        WRITE_A(0, 0, gA0, gA1, gA2, gA3);
        WRITE_A(0, 1, gB0, gB1, gB2, gB3);
        LOAD_A_F(gA0, gA1, gA2, gA3, 1, 0);    // consumed at ph0 (t1.AK0)
        LOAD_A_F(gB0, gB1, gB2, gB3, 1, 1);    // consumed at ph2 (t1.AK1)
        LGW();
        VMW(8);                                 // retire t0.B halves; keep LA groups in flight
        BAR();
    } else {
        STAGE_A_G(0, 0, 0); STAGE_B(0, 0, 0);
        STAGE_A_G(0, 0, 1); STAGE_B(0, 0, 1);
        VMW(4);                                 // t0.K0 landed; t0.K1 in flight
        BAR();
    }

    // ---------------- main loop: 8 iters x 2 K-tiles ----------------
    for (int i = 0; i < 8; ++i) {
        int t1 = 2 * i + 1;
        int t2 = 2 * i + 2; if (t2 > 15) t2 = 15;   // tail clamp (stages never read)
        int t3 = 2 * i + 3; if (t3 > 15) t3 = 15;

        // ph0: compute (t0 buf0, ks0, mh0); stage t1.AK0 -> buf1
        RD_A(0, 0, 0); RD_B(0, 0);
        if constexpr (PASS == 1) {
            WRITE_A(1, 0, gA0, gA1, gA2, gA3);
            LOAD_A_F(gA0, gA1, gA2, gA3, t2, 0);
            LGW();
        } else {
            STAGE_A_G(1, t1, 0);
        }
        BAR(); MFMA16(0); BAR();

        // ph1: (ks0, mh1); stage t1.BK0 -> buf1
        RD_A(0, 0, 1);
        STAGE_B(1, t1, 0);
        BAR(); MFMA16(1);
        if constexpr (PASS == 1) { VMW(6); } else { VMW(4); }
        BAR();

        // ph2: (ks1, mh0); stage t1.AK1 -> buf1
        RD_A(0, 1, 0); RD_B(0, 1);
        if constexpr (PASS == 1) {
            WRITE_A(1, 1, gB0, gB1, gB2, gB3);
            LOAD_A_F(gB0, gB1, gB2, gB3, t2, 1);
            LGW();
        } else {
            STAGE_A_G(1, t1, 1);
        }
        BAR(); MFMA16(0); BAR();

        // ph3: (ks1, mh1); stage t1.BK1 -> buf1
        RD_A(0, 1, 1);
        STAGE_B(1, t1, 1);
        BAR(); MFMA16(1);
        if constexpr (PASS == 1) { VMW(6); } else { VMW(4); }
        BAR();

        // ph4: compute (t1 buf1, ks0, mh0); stage t2.AK0 -> buf0
        RD_A(1, 0, 0); RD_B(1, 0);
        if constexpr (PASS == 1) {
            WRITE_A(0, 0, gA0, gA1, gA2, gA3);
            LOAD_A_F(gA0, gA1, gA2, gA3, t3, 0);
            LGW();
        } else {
            STAGE_A_G(0, t2, 0);
        }
        BAR(); MFMA16(0); BAR();

        // ph5: (ks0, mh1); stage t2.BK0 -> buf0
        RD_A(1, 0, 1);
        STAGE_B(0, t2, 0);
        BAR(); MFMA16(1);
        if constexpr (PASS == 1) { VMW(6); } else { VMW(4); }
        BAR();

        // ph6: (ks1, mh0); stage t2.AK1 -> buf0
        RD_A(1, 1, 0); RD_B(1, 1);
        if constexpr (PASS == 1) {
            WRITE_A(0, 1, gB0, gB1, gB2, gB3);
            LOAD_A_F(gB0, gB1, gB2, gB3, t3, 1);
            LGW();
        } else {
            STAGE_A_G(0, t2, 1);
        }
        BAR(); MFMA16(0); BAR();

        // ph7: (ks1, mh1); stage t2.BK1 -> buf0
        RD_A(1, 1, 1);
        STAGE_B(0, t2, 1);
        BAR(); MFMA16(1);
        if constexpr (PASS == 1) { VMW(6); } else { VMW(4); }
        BAR();
    }

    // ---------------- epilogue ----------------
    int crb = brow * 256 + wr * 128 + kh * 4;
    int ccb = bcol * 256 + wc * 64 + r16;
#pragma unroll
    for (int n = 0; n < 4; ++n) {
        int col = ccb + n * 16;
        float cm, ca;
        if constexpr (PASS == 1) { cm = wst[col]; ca = bias[col]; }
        else                     { cm = dco[col]; ca = ad2[col]; }
#pragma unroll
        for (int m = 0; m < 8; ++m) {
#pragma unroll
            for (int j = 0; j < 4; ++j) {
                size_t idx = (size_t)(crb + m * 16 + j) * DDIM + col;
                float v = acc[m][n][j];
                if constexpr (PASS == 1) {
                    v = (v + ca) * cm;
                    Cb[idx] = __float2bfloat16(v);
                } else {
                    v = v * cm + ca;
                    v = (v >= 0.f) ? v : 0.01f * v;
                    Cf[idx] = v;
                }
            }
        }
    }
#undef STAGE_B
#undef STAGE_A_G
#undef LOAD_A_F
#undef WRITE_A
#undef RD_A
#undef RD_B
#undef MFMA16
}

extern "C" void kernel_launch(void* const* d_in, const int* in_sizes, int n_in,
                              void* d_out, int out_size, void* d_ws, size_t ws_size,
                              hipStream_t stream) {
    const float* x  = (const float*)d_in[0];
    const float* w  = (const float*)d_in[1];
    const float* W  = (const float*)d_in[2];
    const float* b  = (const float*)d_in[3];
    const float* ns = (const float*)d_in[4];
    const float* nr = (const float*)d_in[5];
    float* out = (float*)d_out;

    float* dco = (float*)d_ws;
    float* ad2 = dco + DDIM;
    bf16*  Wb  = (bf16*)((char*)d_ws + 8192);
    bf16*  t   = (bf16*)((char*)d_ws + 8192 + 2097152);

    int M = in_sizes[0] / DDIM;                     // 65536
    int grid = (M / 256) * (DDIM / 256);            // 1024

    prep_kernel<<<DDIM, 64, 0, stream>>>(W, w, b, ns, nr, dco, ad2, Wb);
    gemm8p<1><<<grid, 512, 0, stream>>>(x, nullptr, Wb, w, b, dco, ad2, t, nullptr);
    gemm8p<2><<<grid, 512, 0, stream>>>(nullptr, t, Wb, w, b, dco, ad2, nullptr, out);
}